// Round 8
// baseline (510.652 us; speedup 1.0000x reference)
//
#include <hip/hip_runtime.h>

// ---------------------------------------------------------------------------
// GraphSAGE 2-layer forward on MI355X (gfx950).
//   Layer l: out = deg_inv * segsum((x@Wl.T)[src] -> dst) + x@Wr.T + b
// GEMM-first (linearity). bf16 MFMA GEMM (stage-B-once + M-loop, lgkm-only
// barriers). CSR via two-level LDS-atomic bucket sort.
// Aggregation: fp8 tables stored SLICE-MAJOR [group][node][32B]; blocks are
// XCD-affine (group = blockIdx&7 mapping) so each XCD gathers from a 3.2 MB
// slice that fits its private 4 MB L2 -> compulsory misses only.
// ---------------------------------------------------------------------------

typedef float f32x2 __attribute__((ext_vector_type(2)));
typedef float f32x4 __attribute__((ext_vector_type(4)));
typedef short bf16x8 __attribute__((ext_vector_type(8)));
typedef unsigned short u16;
typedef unsigned char u8;
typedef unsigned short u16x4 __attribute__((ext_vector_type(4)));
typedef unsigned short u16x8 __attribute__((ext_vector_type(8)));

#define SHIFT 9                    // nodes per bucket = 512
#define GB 256                     // blocks in count/scatter passes

__device__ __forceinline__ u16 f2b(float f) {  // f32 -> bf16 RNE (finite)
  unsigned u = __builtin_bit_cast(unsigned, f);
  u += 0x7FFFu + ((u >> 16) & 1u);
  return (u16)(u >> 16);
}
__device__ __forceinline__ float b2f(u16 s) {
  unsigned u = (unsigned)s << 16;
  return __builtin_bit_cast(float, u);
}
__device__ __forceinline__ u8 f2fp8(float f) {  // f32 -> fp8 e4m3 (HW, RNE)
  int p = __builtin_amdgcn_cvt_pk_fp8_f32(f, f, 0, false);
  return (u8)(p & 0xFF);
}
// decode 4 packed fp8 (one dword) -> 4 f32; word-selects are literal consts
__device__ __forceinline__ f32x4 fp8x4_to_f32x4(int w) {
  f32x2 lo = __builtin_amdgcn_cvt_pk_f32_fp8(w, 0);
  f32x2 hi = __builtin_amdgcn_cvt_pk_f32_fp8(w, 1);
  f32x4 r = {lo[0], lo[1], hi[0], hi[1]};
  return r;
}

__device__ __forceinline__ int edge_at(const void* ep, int is64, long long idx) {
  if (is64) return (int)((const long long*)ep)[idx];
  return ((const int*)ep)[idx];
}

// Per-block int64-vs-int32 detection: sample hi words of first 256 entries.
__device__ __forceinline__ int detect64(const void* edges, int* sflag) {
  int t = threadIdx.x;
  if (t == 0) *sflag = 1;
  __syncthreads();
  if (t < 256 && ((const int*)edges)[2 * t + 1] != 0) *sflag = 0;  // benign race
  __syncthreads();
  return *sflag;
}

// Pass A: per-block bucket histogram (LDS atomics), coalesced cnt write.
__global__ __launch_bounds__(256) void countA_kernel(const void* edges,
                                                     int* __restrict__ cnt,
                                                     long long E, int nbuck) {
  __shared__ int h[256];
  __shared__ int sflag;
  int is64 = detect64(edges, &sflag);
  int t = threadIdx.x;
  h[t] = 0;
  __syncthreads();
  long long stride = (long long)GB * 256;
  for (long long i = (long long)blockIdx.x * 256 + t; i < E; i += stride) {
    int dst = edge_at(edges, is64, E + i);
    atomicAdd(&h[dst >> SHIFT], 1);
  }
  __syncthreads();
  if (t < nbuck) cnt[blockIdx.x * nbuck + t] = h[t];
}

// Pass B1: bucket totals + exclusive scan -> bucket_base; also row_ptr[N]=E.
__global__ __launch_bounds__(256) void scanB1_kernel(const int* __restrict__ cnt,
                                                     int* __restrict__ bucket_base,
                                                     int* __restrict__ row_ptr,
                                                     int nbuck, int N) {
  __shared__ int sm[256];
  int t = threadIdx.x;
  int total = 0;
  if (t < nbuck)
    for (int g = 0; g < GB; ++g) total += cnt[g * nbuck + t];
  sm[t] = total;
  __syncthreads();
  for (int o = 1; o < 256; o <<= 1) {
    int x = (t >= o) ? sm[t - o] : 0;
    __syncthreads();
    sm[t] += x;
    __syncthreads();
  }
  if (t < nbuck) bucket_base[t] = sm[t] - total;
  if (t == nbuck - 1) {
    bucket_base[nbuck] = sm[t];
    row_ptr[N] = sm[t];
  }
}

// Pass B2: per-(block,bucket) cursors: cur[g][b] = base[b] + prefix_g cnt[g][b].
__global__ __launch_bounds__(256) void scanB2_kernel(const int* __restrict__ cnt,
                                                     const int* __restrict__ bucket_base,
                                                     int* __restrict__ cur, int nbuck) {
  __shared__ int sm[256];
  int b = blockIdx.x, t = threadIdx.x;
  int v = cnt[t * nbuck + b];
  sm[t] = v;
  __syncthreads();
  for (int o = 1; o < 256; o <<= 1) {
    int x = (t >= o) ? sm[t - o] : 0;
    __syncthreads();
    sm[t] += x;
    __syncthreads();
  }
  cur[t * nbuck + b] = bucket_base[b] + sm[t] - v;
}

// Pass C: scatter edges into bucket-contiguous tmp arrays (LDS cursors).
__global__ __launch_bounds__(256) void scatterC_kernel(const void* edges,
                                                       const int* __restrict__ cur,
                                                       int* __restrict__ tmps,
                                                       u16* __restrict__ tmpd,
                                                       long long E, int nbuck) {
  __shared__ int c[256];
  __shared__ int sflag;
  int is64 = detect64(edges, &sflag);
  int t = threadIdx.x;
  if (t < nbuck) c[t] = cur[blockIdx.x * nbuck + t];
  __syncthreads();
  long long stride = (long long)GB * 256;
  for (long long i = (long long)blockIdx.x * 256 + t; i < E; i += stride) {
    int src = edge_at(edges, is64, i);
    int dst = edge_at(edges, is64, E + i);
    int bk = dst >> SHIFT;
    int pos = atomicAdd(&c[bk], 1);
    tmps[pos] = src;
    tmpd[pos] = (u16)(dst & ((1 << SHIFT) - 1));
  }
}

// Pass D: per-bucket fine counting sort, all cursors in LDS.
__global__ __launch_bounds__(512) void finesort_kernel(const int* __restrict__ tmps,
                                                       const u16* __restrict__ tmpd,
                                                       const int* __restrict__ bucket_base,
                                                       int* __restrict__ row_ptr,
                                                       float* __restrict__ deg_inv,
                                                       int* __restrict__ sorted_src, int N) {
  __shared__ int dg[512];
  __shared__ int sm[512];
  int b = blockIdx.x, t = threadIdx.x;
  int s = bucket_base[b], e = bucket_base[b + 1];
  dg[t] = 0;
  __syncthreads();
  for (int i = s + t; i < e; i += 512) atomicAdd(&dg[tmpd[i]], 1);
  __syncthreads();
  int v = dg[t];
  sm[t] = v;
  __syncthreads();
  for (int o = 1; o < 512; o <<= 1) {
    int x = (t >= o) ? sm[t - o] : 0;
    __syncthreads();
    sm[t] += x;
    __syncthreads();
  }
  int excl = sm[t] - v;
  int node = (b << SHIFT) + t;
  if (node < N) {
    row_ptr[node] = s + excl;
    deg_inv[node] = (v > 0) ? (1.0f / (float)v) : 0.0f;
  }
  sm[t] = s + excl;  // own cell only: becomes the scatter cursor
  __syncthreads();
  for (int i = s + t; i < e; i += 512) {
    int l = tmpd[i];
    int pos = atomicAdd(&sm[l], 1);
    sorted_src[pos] = tmps[i];
  }
}

// ---------------------------------------------------------------------------
// MFMA GEMM, stage-B-once + M-loop, double-buffered A, lgkm-only barrier.
// Gathered-half cols (< split) -> fp8 SLICE-MAJOR cl[gc>>5][N][32];
// self-half cols -> bf16 row-major cr[N][nr].
// ---------------------------------------------------------------------------
template <bool IN_BF16>
__global__ __launch_bounds__(256) void gemm_loop_kernel(
    const void* __restrict__ Xv, const float* __restrict__ Wl, const float* __restrict__ Wr,
    u8* __restrict__ cl, u16* __restrict__ cr, int N, int split, int nr, int mtiles) {
  __shared__ u16 Bs[128][136];
  __shared__ u16 As[2][64][136];
  int tid = threadIdx.x;
  int cb = blockIdx.y * 128;

  const float* Xf = (const float*)Xv;
  const u16* Xb = (const u16*)Xv;
  float4 af[8];
  u16x8 ab[4];

  auto loadA = [&](int mt) {
    long long rb = (long long)mt * 64;
    if constexpr (IN_BF16) {
#pragma unroll
      for (int k = 0; k < 4; ++k) {
        int i = tid + (k << 8);
        int r = i >> 4, c8 = (i & 15) << 3;
        long long gr = rb + r;
        if (gr >= N) gr = N - 1;
        ab[k] = *(const u16x8*)(Xb + gr * 128 + c8);
      }
    } else {
#pragma unroll
      for (int k = 0; k < 8; ++k) {
        int i = tid + (k << 8);
        int r = i >> 5, c4 = (i & 31) << 2;
        long long gr = rb + r;
        if (gr >= N) gr = N - 1;
        af[k] = *(const float4*)(Xf + gr * 128 + c4);
      }
    }
  };
  auto writeA = [&](int buf) {
    if constexpr (IN_BF16) {
#pragma unroll
      for (int k = 0; k < 4; ++k) {
        int i = tid + (k << 8);
        int r = i >> 4, c8 = (i & 15) << 3;
        *(u16x8*)&As[buf][r][c8] = ab[k];
      }
    } else {
#pragma unroll
      for (int k = 0; k < 8; ++k) {
        int i = tid + (k << 8);
        int r = i >> 5, c4 = (i & 31) << 2;
        u16x4 bb = {f2b(af[k].x), f2b(af[k].y), f2b(af[k].z), f2b(af[k].w)};
        *(u16x4*)&As[buf][r][c4] = bb;
      }
    }
  };

  if (blockIdx.x < mtiles) loadA(blockIdx.x);

  // stage B once (weights; L2-resident)
  for (int i = tid; i < 128 * 32; i += 256) {
    int r = i >> 5, c4 = (i & 31) << 2;
    int gc = cb + r;
    const float* wrow = (gc < split) ? (Wl + (long long)gc * 128)
                                     : (Wr + (long long)(gc - split) * 128);
    float4 v = *(const float4*)(wrow + c4);
    u16x4 bb = {f2b(v.x), f2b(v.y), f2b(v.z), f2b(v.w)};
    *(u16x4*)&Bs[r][c4] = bb;
  }

  int wv = tid >> 6, l = tid & 63;
  int wr = (wv & 1) * 32, wc = (wv >> 1) * 64;
  int lr = l & 15, lk = (l >> 4) * 8;

  int lt = 0;
  for (int mt = blockIdx.x; mt < mtiles; mt += gridDim.x, ++lt) {
    int buf = lt & 1;
    writeA(buf);                       // consume prefetch regs -> LDS
    int nmt = mt + gridDim.x;
    if (nmt < mtiles) loadA(nmt);      // next loads stay in flight across barrier
    asm volatile("s_waitcnt lgkmcnt(0)" ::: "memory");  // ds_writes visible
    __builtin_amdgcn_s_barrier();      // NO vmcnt drain

    f32x4 acc[2][4];
#pragma unroll
    for (int i = 0; i < 2; ++i)
#pragma unroll
      for (int j = 0; j < 4; ++j)
#pragma unroll
        for (int r = 0; r < 4; ++r) acc[i][j][r] = 0.f;

#pragma unroll
    for (int ks = 0; ks < 4; ++ks) {
      bf16x8 a[2], b[4];
#pragma unroll
      for (int i = 0; i < 2; ++i)
        a[i] = *(const bf16x8*)&As[buf][wr + i * 16 + lr][ks * 32 + lk];
#pragma unroll
      for (int j = 0; j < 4; ++j)
        b[j] = *(const bf16x8*)&Bs[wc + j * 16 + lr][ks * 32 + lk];
#pragma unroll
      for (int i = 0; i < 2; ++i)
#pragma unroll
        for (int j = 0; j < 4; ++j)
          acc[i][j] = __builtin_amdgcn_mfma_f32_16x16x32_bf16(a[i], b[j], acc[i][j], 0, 0, 0);
    }

    // C/D layout: col = lane&15, row = (lane>>4)*4 + reg
    long long rb = (long long)mt * 64;
#pragma unroll
    for (int i = 0; i < 2; ++i) {
#pragma unroll
      for (int j = 0; j < 4; ++j) {
        int gc = cb + wc + j * 16 + (l & 15);
#pragma unroll
        for (int r = 0; r < 4; ++r) {
          long long gr = rb + wr + i * 16 + ((l >> 4) << 2) + r;
          if (gr < N) {
            if (gc < split)
              cl[((long long)(gc >> 5) * N + gr) * 32 + (gc & 31)] = f2fp8(acc[i][j][r]);
            else
              cr[gr * nr + (gc - split)] = f2b(acc[i][j][r]);
          }
        }
      }
    }
  }
}

// Layer-1 aggregate + combine + ReLU. 4 ch-groups of 32; group = (bid&7)>>1
// (XCD pairs). 8-lane group per node (8 consecutive nodes/wave), lane owns
// 4 fp8 channels; no cross-lane reduction. Slice (3.2 MB) is L2-resident.
__global__ __launch_bounds__(256) void agg1_kernel(const u8* __restrict__ t1l,
                                                   const u16* __restrict__ t1r,
                                                   const int* __restrict__ row_ptr,
                                                   const int* __restrict__ sorted_src,
                                                   const float* __restrict__ deg_inv,
                                                   const float* __restrict__ b1,
                                                   u16* __restrict__ h, int N) {
  int g = (blockIdx.x & 7) >> 1;          // 4 channel groups
  int w = threadIdx.x >> 6, l = threadIdx.x & 63;
  int q = l >> 3, ch = l & 7;             // node sub-group, dword-channel
  const u8* base = t1l + (long long)g * N * 32 + ch * 4;
  f32x4 bb = *(const f32x4*)(b1 + g * 32 + ch * 4);
  int wid = (int)(blockIdx.x >> 3) * 4 + w;
  int wstep = (int)(gridDim.x >> 3) * 4;
  for (long long nb = (long long)wid * 8; nb < N; nb += (long long)wstep * 8) {
    int n = (int)nb + q;
    bool act = n < N;
    int beg = act ? row_ptr[n] : 0;
    int end = act ? row_ptr[n + 1] : 0;
    f32x4 acc = {0.f, 0.f, 0.f, 0.f};
    for (int e = beg; e < end; ++e) {
      int src = sorted_src[e];
      int wd = *(const int*)(base + (long long)src * 32);
      f32x4 d = fp8x4_to_f32x4(wd);
      acc += d;
    }
    if (act) {
      float di = deg_inv[n];
      u16x4 tr = *(const u16x4*)(t1r + (long long)n * 128 + g * 32 + ch * 4);
      u16x4 o;
#pragma unroll
      for (int k = 0; k < 4; ++k)
        o[k] = f2b(fmaxf(acc[k] * di + b2f(tr[k]) + bb[k], 0.f));
      *(u16x4*)(h + (long long)n * 128 + g * 32 + ch * 4) = o;
    }
  }
}

// Layer-2 aggregate + combine. 2 ch-groups of 32; group = (bid&7)>>2
// (XCD quads). Same node-per-8-lane structure. f32 output.
__global__ __launch_bounds__(256) void agg2_kernel(const u8* __restrict__ t3l,
                                                   const u16* __restrict__ t3r,
                                                   const int* __restrict__ row_ptr,
                                                   const int* __restrict__ sorted_src,
                                                   const float* __restrict__ deg_inv,
                                                   const float* __restrict__ b2,
                                                   float* __restrict__ out, int N) {
  int g = (blockIdx.x & 7) >> 2;          // 2 channel groups
  int w = threadIdx.x >> 6, l = threadIdx.x & 63;
  int q = l >> 3, ch = l & 7;
  const u8* base = t3l + (long long)g * N * 32 + ch * 4;
  f32x4 bb = *(const f32x4*)(b2 + g * 32 + ch * 4);
  int wid = (int)(blockIdx.x >> 3) * 4 + w;
  int wstep = (int)(gridDim.x >> 3) * 4;
  for (long long nb = (long long)wid * 8; nb < N; nb += (long long)wstep * 8) {
    int n = (int)nb + q;
    bool act = n < N;
    int beg = act ? row_ptr[n] : 0;
    int end = act ? row_ptr[n + 1] : 0;
    f32x4 acc = {0.f, 0.f, 0.f, 0.f};
    for (int e = beg; e < end; ++e) {
      int src = sorted_src[e];
      int wd = *(const int*)(base + (long long)src * 32);
      f32x4 d = fp8x4_to_f32x4(wd);
      acc += d;
    }
    if (act) {
      float di = deg_inv[n];
      u16x4 tr = *(const u16x4*)(t3r + (long long)n * 64 + g * 32 + ch * 4);
      f32x4 o;
#pragma unroll
      for (int k = 0; k < 4; ++k) o[k] = acc[k] * di + b2f(tr[k]) + bb[k];
      *(f32x4*)(out + (long long)n * 64 + g * 32 + ch * 4) = o;
    }
  }
}

extern "C" void kernel_launch(void* const* d_in, const int* in_sizes, int n_in,
                              void* d_out, int out_size, void* d_ws, size_t ws_size,
                              hipStream_t stream) {
  const float* x = (const float*)d_in[0];
  const void* edges = d_in[1];
  const float* W1l = (const float*)d_in[2];
  const float* W1r = (const float*)d_in[3];
  const float* b1 = (const float*)d_in[4];
  const float* W2l = (const float*)d_in[5];
  const float* W2r = (const float*)d_in[6];
  const float* b2 = (const float*)d_in[7];
  float* out = (float*)d_out;

  int N = in_sizes[0] / 128;
  long long E = (long long)in_sizes[1] / 2;
  int nbuck = (N + (1 << SHIFT) - 1) >> SHIFT;  // 196 for N=100000 (<=256 required)

  auto align = [](size_t v) { return (v + 255) & ~(size_t)255; };
  char* ws = (char*)d_ws;
  size_t o = 0;
  int* bucket_base = (int*)(ws + o);  o += align((size_t)(nbuck + 1) * 4);
  int* cnt = (int*)(ws + o);          o += align((size_t)GB * nbuck * 4);
  int* cur = (int*)(ws + o);          o += align((size_t)GB * nbuck * 4);
  int* row_ptr = (int*)(ws + o);      o += align((size_t)(N + 1) * 4);
  float* deg_inv = (float*)(ws + o);  o += align((size_t)N * 4);
  int* sorted_src = (int*)(ws + o);   o += align((size_t)E * 4);
  int* tmps = (int*)(ws + o);         o += align((size_t)E * 4);
  u16* tmpd = (u16*)(ws + o);         o += align((size_t)E * 2);
  u8* t1l = (u8*)(ws + o);            o += align((size_t)N * 128);  // [4][N][32]
  u16* t1r = (u16*)(ws + o);          o += align((size_t)N * 128 * 2);
  u16* h = (u16*)(ws + o);            o += align((size_t)N * 128 * 2);
  u8* t3l = t1l;     // aliases: t1 dead once h computed; [2][N][32]
  u16* t3r = t1r;

  countA_kernel<<<GB, 256, 0, stream>>>(edges, cnt, E, nbuck);
  scanB1_kernel<<<1, 256, 0, stream>>>(cnt, bucket_base, row_ptr, nbuck, N);
  scanB2_kernel<<<nbuck, 256, 0, stream>>>(cnt, bucket_base, cur, nbuck);
  scatterC_kernel<<<GB, 256, 0, stream>>>(edges, cur, tmps, tmpd, E, nbuck);
  finesort_kernel<<<nbuck, 512, 0, stream>>>(tmps, tmpd, bucket_base, row_ptr, deg_inv,
                                             sorted_src, N);

  int mb = (N + 63) / 64;
  // Layer 1: [t1l | t1r] = x @ [W1_l | W1_r]^T  (split=128, nr=128, 2 col-tiles)
  gemm_loop_kernel<false><<<dim3(256, 2), 256, 0, stream>>>(x, W1l, W1r, t1l, t1r, N, 128, 128, mb);
  agg1_kernel<<<6400, 256, 0, stream>>>(t1l, t1r, row_ptr, sorted_src, deg_inv, b1, h, N);

  // Layer 2: [t3l | t3r] = h @ [W2_l | W2_r]^T  (split=64, nr=64, 1 col-tile)
  gemm_loop_kernel<true><<<dim3(512, 1), 256, 0, stream>>>(h, W2l, W2r, t3l, t3r, N, 64, 64, mb);
  agg2_kernel<<<6400, 256, 0, stream>>>(t3l, t3r, row_ptr, sorted_src, deg_inv, b2, out, N);
}

// Round 9
// 204.077 us; speedup vs baseline: 2.5023x; 2.5023x over previous
//
#include <hip/hip_runtime.h>

// ---------------------------------------------------------------------------
// GraphSAGE 2-layer forward on MI355X (gfx950).
//   Layer l: out = deg_inv * segsum((x@Wl.T)[src] -> dst) + x@Wr.T + b
// GEMM-first (linearity). bf16 MFMA GEMM (stage-B-once + M-loop, lgkm-only
// barriers). CSR via two-level LDS-atomic bucket sort; sorted_src holds
// PRE-SHIFTED byte offsets (src<<6) so gathers need no 64-bit address math.
// Aggregation: fp8 row-major tables; lane-wide rows (uint2/uint per lane)
// give 4 edges per VMEM instruction; packed cvt_pk_f32_fp8 + pk_add_f32.
// ---------------------------------------------------------------------------

typedef float f32x2 __attribute__((ext_vector_type(2)));
typedef float f32x4 __attribute__((ext_vector_type(4)));
typedef short bf16x8 __attribute__((ext_vector_type(8)));
typedef unsigned short u16;
typedef unsigned char u8;
typedef unsigned short u16x4 __attribute__((ext_vector_type(4)));
typedef unsigned short u16x8 __attribute__((ext_vector_type(8)));

#define SHIFT 9                    // nodes per bucket = 512
#define GB 256                     // blocks in count/scatter passes

__device__ __forceinline__ u16 f2b(float f) {  // f32 -> bf16 RNE (finite)
  unsigned u = __builtin_bit_cast(unsigned, f);
  u += 0x7FFFu + ((u >> 16) & 1u);
  return (u16)(u >> 16);
}
__device__ __forceinline__ float b2f(u16 s) {
  unsigned u = (unsigned)s << 16;
  return __builtin_bit_cast(float, u);
}
__device__ __forceinline__ u8 f2fp8(float f) {  // f32 -> fp8 e4m3 (HW, RNE)
  int p = __builtin_amdgcn_cvt_pk_fp8_f32(f, f, 0, false);
  return (u8)(p & 0xFF);
}

__device__ __forceinline__ int edge_at(const void* ep, int is64, long long idx) {
  if (is64) return (int)((const long long*)ep)[idx];
  return ((const int*)ep)[idx];
}

// Per-block int64-vs-int32 detection: sample hi words of first 256 entries.
__device__ __forceinline__ int detect64(const void* edges, int* sflag) {
  int t = threadIdx.x;
  if (t == 0) *sflag = 1;
  __syncthreads();
  if (t < 256 && ((const int*)edges)[2 * t + 1] != 0) *sflag = 0;  // benign race
  __syncthreads();
  return *sflag;
}

// Pass A: per-block bucket histogram (LDS atomics), coalesced cnt write.
__global__ __launch_bounds__(256) void countA_kernel(const void* edges,
                                                     int* __restrict__ cnt,
                                                     long long E, int nbuck) {
  __shared__ int h[256];
  __shared__ int sflag;
  int is64 = detect64(edges, &sflag);
  int t = threadIdx.x;
  h[t] = 0;
  __syncthreads();
  long long stride = (long long)GB * 256;
  for (long long i = (long long)blockIdx.x * 256 + t; i < E; i += stride) {
    int dst = edge_at(edges, is64, E + i);
    atomicAdd(&h[dst >> SHIFT], 1);
  }
  __syncthreads();
  if (t < nbuck) cnt[blockIdx.x * nbuck + t] = h[t];
}

// Pass B1: bucket totals + exclusive scan -> bucket_base; also row_ptr[N]=E.
__global__ __launch_bounds__(256) void scanB1_kernel(const int* __restrict__ cnt,
                                                     int* __restrict__ bucket_base,
                                                     int* __restrict__ row_ptr,
                                                     int nbuck, int N) {
  __shared__ int sm[256];
  int t = threadIdx.x;
  int total = 0;
  if (t < nbuck)
    for (int g = 0; g < GB; ++g) total += cnt[g * nbuck + t];
  sm[t] = total;
  __syncthreads();
  for (int o = 1; o < 256; o <<= 1) {
    int x = (t >= o) ? sm[t - o] : 0;
    __syncthreads();
    sm[t] += x;
    __syncthreads();
  }
  if (t < nbuck) bucket_base[t] = sm[t] - total;
  if (t == nbuck - 1) {
    bucket_base[nbuck] = sm[t];
    row_ptr[N] = sm[t];
  }
}

// Pass B2: per-(block,bucket) cursors: cur[g][b] = base[b] + prefix_g cnt[g][b].
__global__ __launch_bounds__(256) void scanB2_kernel(const int* __restrict__ cnt,
                                                     const int* __restrict__ bucket_base,
                                                     int* __restrict__ cur, int nbuck) {
  __shared__ int sm[256];
  int b = blockIdx.x, t = threadIdx.x;
  int v = cnt[t * nbuck + b];
  sm[t] = v;
  __syncthreads();
  for (int o = 1; o < 256; o <<= 1) {
    int x = (t >= o) ? sm[t - o] : 0;
    __syncthreads();
    sm[t] += x;
    __syncthreads();
  }
  cur[t * nbuck + b] = bucket_base[b] + sm[t] - v;
}

// Pass C: scatter edges into bucket-contiguous tmp arrays (LDS cursors).
__global__ __launch_bounds__(256) void scatterC_kernel(const void* edges,
                                                       const int* __restrict__ cur,
                                                       int* __restrict__ tmps,
                                                       u16* __restrict__ tmpd,
                                                       long long E, int nbuck) {
  __shared__ int c[256];
  __shared__ int sflag;
  int is64 = detect64(edges, &sflag);
  int t = threadIdx.x;
  if (t < nbuck) c[t] = cur[blockIdx.x * nbuck + t];
  __syncthreads();
  long long stride = (long long)GB * 256;
  for (long long i = (long long)blockIdx.x * 256 + t; i < E; i += stride) {
    int src = edge_at(edges, is64, i);
    int dst = edge_at(edges, is64, E + i);
    int bk = dst >> SHIFT;
    int pos = atomicAdd(&c[bk], 1);
    tmps[pos] = src;
    tmpd[pos] = (u16)(dst & ((1 << SHIFT) - 1));
  }
}

// Pass D: per-bucket fine counting sort, all cursors in LDS.
// sorted_src stores PRE-SHIFTED byte offsets: src<<6 (64B granularity).
__global__ __launch_bounds__(512) void finesort_kernel(const int* __restrict__ tmps,
                                                       const u16* __restrict__ tmpd,
                                                       const int* __restrict__ bucket_base,
                                                       int* __restrict__ row_ptr,
                                                       float* __restrict__ deg_inv,
                                                       int* __restrict__ sorted_src, int N) {
  __shared__ int dg[512];
  __shared__ int sm[512];
  int b = blockIdx.x, t = threadIdx.x;
  int s = bucket_base[b], e = bucket_base[b + 1];
  dg[t] = 0;
  __syncthreads();
  for (int i = s + t; i < e; i += 512) atomicAdd(&dg[tmpd[i]], 1);
  __syncthreads();
  int v = dg[t];
  sm[t] = v;
  __syncthreads();
  for (int o = 1; o < 512; o <<= 1) {
    int x = (t >= o) ? sm[t - o] : 0;
    __syncthreads();
    sm[t] += x;
    __syncthreads();
  }
  int excl = sm[t] - v;
  int node = (b << SHIFT) + t;
  if (node < N) {
    row_ptr[node] = s + excl;
    deg_inv[node] = (v > 0) ? (1.0f / (float)v) : 0.0f;
  }
  sm[t] = s + excl;  // own cell only: becomes the scatter cursor
  __syncthreads();
  for (int i = s + t; i < e; i += 512) {
    int l = tmpd[i];
    int pos = atomicAdd(&sm[l], 1);
    sorted_src[pos] = tmps[i] << 6;   // byte offset, 64B unit
  }
}

// ---------------------------------------------------------------------------
// MFMA GEMM, stage-B-once + M-loop, double-buffered A, lgkm-only barrier.
// Gathered-half cols (< split) -> fp8 row-major cl[N][split];
// self-half cols -> bf16 row-major cr[N][nr].
// ---------------------------------------------------------------------------
template <bool IN_BF16>
__global__ __launch_bounds__(256) void gemm_loop_kernel(
    const void* __restrict__ Xv, const float* __restrict__ Wl, const float* __restrict__ Wr,
    u8* __restrict__ cl, u16* __restrict__ cr, int N, int split, int nr, int mtiles) {
  __shared__ u16 Bs[128][136];
  __shared__ u16 As[2][64][136];
  int tid = threadIdx.x;
  int cb = blockIdx.y * 128;

  const float* Xf = (const float*)Xv;
  const u16* Xb = (const u16*)Xv;
  float4 af[8];
  u16x8 ab[4];

  auto loadA = [&](int mt) {
    long long rb = (long long)mt * 64;
    if constexpr (IN_BF16) {
#pragma unroll
      for (int k = 0; k < 4; ++k) {
        int i = tid + (k << 8);
        int r = i >> 4, c8 = (i & 15) << 3;
        long long gr = rb + r;
        if (gr >= N) gr = N - 1;
        ab[k] = *(const u16x8*)(Xb + gr * 128 + c8);
      }
    } else {
#pragma unroll
      for (int k = 0; k < 8; ++k) {
        int i = tid + (k << 8);
        int r = i >> 5, c4 = (i & 31) << 2;
        long long gr = rb + r;
        if (gr >= N) gr = N - 1;
        af[k] = *(const float4*)(Xf + gr * 128 + c4);
      }
    }
  };
  auto writeA = [&](int buf) {
    if constexpr (IN_BF16) {
#pragma unroll
      for (int k = 0; k < 4; ++k) {
        int i = tid + (k << 8);
        int r = i >> 4, c8 = (i & 15) << 3;
        *(u16x8*)&As[buf][r][c8] = ab[k];
      }
    } else {
#pragma unroll
      for (int k = 0; k < 8; ++k) {
        int i = tid + (k << 8);
        int r = i >> 5, c4 = (i & 31) << 2;
        u16x4 bb = {f2b(af[k].x), f2b(af[k].y), f2b(af[k].z), f2b(af[k].w)};
        *(u16x4*)&As[buf][r][c4] = bb;
      }
    }
  };

  if (blockIdx.x < mtiles) loadA(blockIdx.x);

  // stage B once (weights; L2-resident)
  for (int i = tid; i < 128 * 32; i += 256) {
    int r = i >> 5, c4 = (i & 31) << 2;
    int gc = cb + r;
    const float* wrow = (gc < split) ? (Wl + (long long)gc * 128)
                                     : (Wr + (long long)(gc - split) * 128);
    float4 v = *(const float4*)(wrow + c4);
    u16x4 bb = {f2b(v.x), f2b(v.y), f2b(v.z), f2b(v.w)};
    *(u16x4*)&Bs[r][c4] = bb;
  }

  int wv = tid >> 6, l = tid & 63;
  int wr = (wv & 1) * 32, wc = (wv >> 1) * 64;
  int lr = l & 15, lk = (l >> 4) * 8;

  int lt = 0;
  for (int mt = blockIdx.x; mt < mtiles; mt += gridDim.x, ++lt) {
    int buf = lt & 1;
    writeA(buf);                       // consume prefetch regs -> LDS
    int nmt = mt + gridDim.x;
    if (nmt < mtiles) loadA(nmt);      // next loads stay in flight across barrier
    asm volatile("s_waitcnt lgkmcnt(0)" ::: "memory");  // ds_writes visible
    __builtin_amdgcn_s_barrier();      // NO vmcnt drain

    f32x4 acc[2][4];
#pragma unroll
    for (int i = 0; i < 2; ++i)
#pragma unroll
      for (int j = 0; j < 4; ++j)
#pragma unroll
        for (int r = 0; r < 4; ++r) acc[i][j][r] = 0.f;

#pragma unroll
    for (int ks = 0; ks < 4; ++ks) {
      bf16x8 a[2], b[4];
#pragma unroll
      for (int i = 0; i < 2; ++i)
        a[i] = *(const bf16x8*)&As[buf][wr + i * 16 + lr][ks * 32 + lk];
#pragma unroll
      for (int j = 0; j < 4; ++j)
        b[j] = *(const bf16x8*)&Bs[wc + j * 16 + lr][ks * 32 + lk];
#pragma unroll
      for (int i = 0; i < 2; ++i)
#pragma unroll
        for (int j = 0; j < 4; ++j)
          acc[i][j] = __builtin_amdgcn_mfma_f32_16x16x32_bf16(a[i], b[j], acc[i][j], 0, 0, 0);
    }

    // C/D layout: col = lane&15, row = (lane>>4)*4 + reg
    long long rb = (long long)mt * 64;
#pragma unroll
    for (int i = 0; i < 2; ++i) {
#pragma unroll
      for (int j = 0; j < 4; ++j) {
        int gc = cb + wc + j * 16 + (l & 15);
#pragma unroll
        for (int r = 0; r < 4; ++r) {
          long long gr = rb + wr + i * 16 + ((l >> 4) << 2) + r;
          if (gr < N) {
            if (gc < split) cl[gr * split + gc] = f2fp8(acc[i][j][r]);
            else cr[gr * nr + (gc - split)] = f2b(acc[i][j][r]);
          }
        }
      }
    }
  }
}

// Layer-1 aggregate + combine + ReLU. Wave per node. 4 quarters x 16 lanes;
// lane loads uint2 (8 fp8 ch) -> 4 edges per VMEM instruction, unroll 2.
// Gathers use 32-bit saddr+voffset (srcoff pre-shifted, base uniform).
__global__ __launch_bounds__(256) void agg1_kernel(const u8* __restrict__ t1l,
                                                   const u16* __restrict__ t1r,
                                                   const int* __restrict__ row_ptr,
                                                   const int* __restrict__ srcoff,
                                                   const float* __restrict__ deg_inv,
                                                   const float* __restrict__ b1,
                                                   u16* __restrict__ h, int N) {
  int node = (int)(((long long)blockIdx.x * 256 + threadIdx.x) >> 6);
  int lane = threadIdx.x & 63;
  if (node >= N) return;
  int q = lane >> 4;        // edge slot within 4-edge group
  int c = lane & 15;        // channel octet: ch c*8 .. c*8+7
  unsigned loff = (unsigned)c * 8;

  int beg = row_ptr[node], end = row_ptr[node + 1];
  float di = deg_inv[node];
  // hoisted self path (one wave-load each, overlaps gather loop)
  u16x8 tr = *(const u16x8*)(t1r + (long long)node * 128 + c * 8);
  f32x4 bb0 = *(const f32x4*)(b1 + c * 8);
  f32x4 bb1 = *(const f32x4*)(b1 + c * 8 + 4);

  f32x2 a0 = {0.f, 0.f}, a1 = {0.f, 0.f}, a2 = {0.f, 0.f}, a3 = {0.f, 0.f};
  int e = beg + q;
  for (; e + 4 < end; e += 8) {   // this quarter: edges e and e+4
    int o0 = srcoff[e], o1 = srcoff[e + 4];
    uint2 w0 = *(const uint2*)(t1l + ((unsigned)(o0 << 1) + loff));
    uint2 w1 = *(const uint2*)(t1l + ((unsigned)(o1 << 1) + loff));
    a0 += __builtin_amdgcn_cvt_pk_f32_fp8((int)w0.x, 0);
    a1 += __builtin_amdgcn_cvt_pk_f32_fp8((int)w0.x, 1);
    a2 += __builtin_amdgcn_cvt_pk_f32_fp8((int)w0.y, 0);
    a3 += __builtin_amdgcn_cvt_pk_f32_fp8((int)w0.y, 1);
    a0 += __builtin_amdgcn_cvt_pk_f32_fp8((int)w1.x, 0);
    a1 += __builtin_amdgcn_cvt_pk_f32_fp8((int)w1.x, 1);
    a2 += __builtin_amdgcn_cvt_pk_f32_fp8((int)w1.y, 0);
    a3 += __builtin_amdgcn_cvt_pk_f32_fp8((int)w1.y, 1);
  }
  for (; e < end; e += 4) {
    int o0 = srcoff[e];
    uint2 w0 = *(const uint2*)(t1l + ((unsigned)(o0 << 1) + loff));
    a0 += __builtin_amdgcn_cvt_pk_f32_fp8((int)w0.x, 0);
    a1 += __builtin_amdgcn_cvt_pk_f32_fp8((int)w0.x, 1);
    a2 += __builtin_amdgcn_cvt_pk_f32_fp8((int)w0.y, 0);
    a3 += __builtin_amdgcn_cvt_pk_f32_fp8((int)w0.y, 1);
  }
  // reduce across the 4 quarters
#pragma unroll
  for (int j = 0; j < 2; ++j) {
    a0[j] += __shfl_xor(a0[j], 16); a0[j] += __shfl_xor(a0[j], 32);
    a1[j] += __shfl_xor(a1[j], 16); a1[j] += __shfl_xor(a1[j], 32);
    a2[j] += __shfl_xor(a2[j], 16); a2[j] += __shfl_xor(a2[j], 32);
    a3[j] += __shfl_xor(a3[j], 16); a3[j] += __shfl_xor(a3[j], 32);
  }
  if (q == 0) {
    u16x8 o;
    o[0] = f2b(fmaxf(a0[0] * di + b2f(tr[0]) + bb0[0], 0.f));
    o[1] = f2b(fmaxf(a0[1] * di + b2f(tr[1]) + bb0[1], 0.f));
    o[2] = f2b(fmaxf(a1[0] * di + b2f(tr[2]) + bb0[2], 0.f));
    o[3] = f2b(fmaxf(a1[1] * di + b2f(tr[3]) + bb0[3], 0.f));
    o[4] = f2b(fmaxf(a2[0] * di + b2f(tr[4]) + bb1[0], 0.f));
    o[5] = f2b(fmaxf(a2[1] * di + b2f(tr[5]) + bb1[1], 0.f));
    o[6] = f2b(fmaxf(a3[0] * di + b2f(tr[6]) + bb1[2], 0.f));
    o[7] = f2b(fmaxf(a3[1] * di + b2f(tr[7]) + bb1[3], 0.f));
    *(u16x8*)(h + (long long)node * 128 + c * 8) = o;
  }
}

// Layer-2 aggregate + combine. Wave per node. 4 quarters x 16 lanes; lane
// loads uint (4 fp8 ch) -> 4 edges per VMEM instruction, unroll 2.
__global__ __launch_bounds__(256) void agg2_kernel(const u8* __restrict__ t3l,
                                                   const u16* __restrict__ t3r,
                                                   const int* __restrict__ row_ptr,
                                                   const int* __restrict__ srcoff,
                                                   const float* __restrict__ deg_inv,
                                                   const float* __restrict__ b2,
                                                   float* __restrict__ out, int N) {
  int node = (int)(((long long)blockIdx.x * 256 + threadIdx.x) >> 6);
  int lane = threadIdx.x & 63;
  if (node >= N) return;
  int q = lane >> 4;        // edge slot
  int c = lane & 15;        // channel quad: ch c*4 .. c*4+3
  unsigned loff = (unsigned)c * 4;

  int beg = row_ptr[node], end = row_ptr[node + 1];
  float di = deg_inv[node];
  u16x4 tr = *(const u16x4*)(t3r + (long long)node * 64 + c * 4);
  f32x4 bb = *(const f32x4*)(b2 + c * 4);

  f32x2 a0 = {0.f, 0.f}, a1 = {0.f, 0.f};
  int e = beg + q;
  for (; e + 4 < end; e += 8) {
    int o0 = srcoff[e], o1 = srcoff[e + 4];
    unsigned w0 = *(const unsigned*)(t3l + ((unsigned)o0 + loff));
    unsigned w1 = *(const unsigned*)(t3l + ((unsigned)o1 + loff));
    a0 += __builtin_amdgcn_cvt_pk_f32_fp8((int)w0, 0);
    a1 += __builtin_amdgcn_cvt_pk_f32_fp8((int)w0, 1);
    a0 += __builtin_amdgcn_cvt_pk_f32_fp8((int)w1, 0);
    a1 += __builtin_amdgcn_cvt_pk_f32_fp8((int)w1, 1);
  }
  for (; e < end; e += 4) {
    int o0 = srcoff[e];
    unsigned w0 = *(const unsigned*)(t3l + ((unsigned)o0 + loff));
    a0 += __builtin_amdgcn_cvt_pk_f32_fp8((int)w0, 0);
    a1 += __builtin_amdgcn_cvt_pk_f32_fp8((int)w0, 1);
  }
#pragma unroll
  for (int j = 0; j < 2; ++j) {
    a0[j] += __shfl_xor(a0[j], 16); a0[j] += __shfl_xor(a0[j], 32);
    a1[j] += __shfl_xor(a1[j], 16); a1[j] += __shfl_xor(a1[j], 32);
  }
  if (q == 0) {
    f32x4 o;
    o[0] = a0[0] * di + b2f(tr[0]) + bb[0];
    o[1] = a0[1] * di + b2f(tr[1]) + bb[1];
    o[2] = a1[0] * di + b2f(tr[2]) + bb[2];
    o[3] = a1[1] * di + b2f(tr[3]) + bb[3];
    *(f32x4*)(out + (long long)node * 64 + c * 4) = o;
  }
}

extern "C" void kernel_launch(void* const* d_in, const int* in_sizes, int n_in,
                              void* d_out, int out_size, void* d_ws, size_t ws_size,
                              hipStream_t stream) {
  const float* x = (const float*)d_in[0];
  const void* edges = d_in[1];
  const float* W1l = (const float*)d_in[2];
  const float* W1r = (const float*)d_in[3];
  const float* b1 = (const float*)d_in[4];
  const float* W2l = (const float*)d_in[5];
  const float* W2r = (const float*)d_in[6];
  const float* b2 = (const float*)d_in[7];
  float* out = (float*)d_out;

  int N = in_sizes[0] / 128;
  long long E = (long long)in_sizes[1] / 2;
  int nbuck = (N + (1 << SHIFT) - 1) >> SHIFT;  // 196 for N=100000 (<=256 required)

  auto align = [](size_t v) { return (v + 255) & ~(size_t)255; };
  char* ws = (char*)d_ws;
  size_t o = 0;
  int* bucket_base = (int*)(ws + o);  o += align((size_t)(nbuck + 1) * 4);
  int* cnt = (int*)(ws + o);          o += align((size_t)GB * nbuck * 4);
  int* cur = (int*)(ws + o);          o += align((size_t)GB * nbuck * 4);
  int* row_ptr = (int*)(ws + o);      o += align((size_t)(N + 1) * 4);
  float* deg_inv = (float*)(ws + o);  o += align((size_t)N * 4);
  int* sorted_src = (int*)(ws + o);   o += align((size_t)E * 4);
  int* tmps = (int*)(ws + o);         o += align((size_t)E * 4);
  u16* tmpd = (u16*)(ws + o);         o += align((size_t)E * 2);
  u8* t1l = (u8*)(ws + o);            o += align((size_t)N * 128);  // [N][128] fp8
  u16* t1r = (u16*)(ws + o);          o += align((size_t)N * 128 * 2);
  u16* h = (u16*)(ws + o);            o += align((size_t)N * 128 * 2);
  u8* t3l = t1l;     // aliases: t1 dead once h computed; [N][64] fp8
  u16* t3r = t1r;

  countA_kernel<<<GB, 256, 0, stream>>>(edges, cnt, E, nbuck);
  scanB1_kernel<<<1, 256, 0, stream>>>(cnt, bucket_base, row_ptr, nbuck, N);
  scanB2_kernel<<<nbuck, 256, 0, stream>>>(cnt, bucket_base, cur, nbuck);
  scatterC_kernel<<<GB, 256, 0, stream>>>(edges, cur, tmps, tmpd, E, nbuck);
  finesort_kernel<<<nbuck, 512, 0, stream>>>(tmps, tmpd, bucket_base, row_ptr, deg_inv,
                                             sorted_src, N);

  int mb = (N + 63) / 64;
  // Layer 1: [t1l | t1r] = x @ [W1_l | W1_r]^T  (split=128, nr=128, 2 col-tiles)
  gemm_loop_kernel<false><<<dim3(256, 2), 256, 0, stream>>>(x, W1l, W1r, t1l, t1r, N, 128, 128, mb);
  agg1_kernel<<<(N + 3) / 4, 256, 0, stream>>>(t1l, t1r, row_ptr, sorted_src, deg_inv, b1, h, N);

  // Layer 2: [t3l | t3r] = h @ [W2_l | W2_r]^T  (split=64, nr=64, 1 col-tile)
  gemm_loop_kernel<true><<<dim3(512, 1), 256, 0, stream>>>(h, W2l, W2r, t3l, t3r, N, 64, 64, mb);
  agg2_kernel<<<(N + 3) / 4, 256, 0, stream>>>(t3l, t3r, row_ptr, sorted_src, deg_inv, b2, out, N);
}

// Round 10
// 197.465 us; speedup vs baseline: 2.5860x; 1.0335x over previous
//
#include <hip/hip_runtime.h>

// ---------------------------------------------------------------------------
// GraphSAGE 2-layer forward on MI355X (gfx950).
//   Layer l: out = deg_inv * segsum((x@Wl.T)[src] -> dst) + x@Wr.T + b
// GEMM-first (linearity). bf16 MFMA GEMM (stage-B-once + M-loop, lgkm-only
// barriers) with OPERAND-SWAPPED MFMA: lane holds 4 consecutive output cols
// -> vectorized u8x4/u16x4 epilogue stores (4x fewer VMEM instrs), packed
// cvt_pk_bf16/fp8 conversions. CSR via two-level LDS-atomic bucket sort;
// srcoff pre-shifted. fp8 gather tables, packed-decode aggregation.
// ---------------------------------------------------------------------------

typedef float f32x2 __attribute__((ext_vector_type(2)));
typedef float f32x4 __attribute__((ext_vector_type(4)));
typedef short bf16x8 __attribute__((ext_vector_type(8)));
typedef unsigned short u16;
typedef unsigned char u8;
typedef unsigned short u16x4 __attribute__((ext_vector_type(4)));
typedef unsigned short u16x8 __attribute__((ext_vector_type(8)));

#define SHIFT 9                    // nodes per bucket = 512
#define GB 256                     // blocks in count/scatter passes

__device__ __forceinline__ u16 f2b(float f) {  // f32 -> bf16 RNE (finite)
  unsigned u = __builtin_bit_cast(unsigned, f);
  u += 0x7FFFu + ((u >> 16) & 1u);
  return (u16)(u >> 16);
}
__device__ __forceinline__ float b2f(u16 s) {
  unsigned u = (unsigned)s << 16;
  return __builtin_bit_cast(float, u);
}
__device__ __forceinline__ u8 f2fp8(float f) {  // f32 -> fp8 e4m3 (HW, RNE)
  int p = __builtin_amdgcn_cvt_pk_fp8_f32(f, f, 0, false);
  return (u8)(p & 0xFF);
}
// packed f32 pair -> [bf16(lo) | bf16(hi)<<16] (HW RNE, same as f2b)
__device__ __forceinline__ unsigned cvt_pk_bf16(float lo, float hi) {
  unsigned r;
  asm("v_cvt_pk_bf16_f32 %0, %1, %2" : "=v"(r) : "v"(lo), "v"(hi));
  return r;
}
// 4 f32 -> 4 packed fp8 bytes
__device__ __forceinline__ unsigned cvt_pk_fp8x4(float a, float b, float c, float d) {
  int p = __builtin_amdgcn_cvt_pk_fp8_f32(a, b, 0, false);
  p = __builtin_amdgcn_cvt_pk_fp8_f32(c, d, p, true);
  return (unsigned)p;
}

__device__ __forceinline__ int edge_at(const void* ep, int is64, long long idx) {
  if (is64) return (int)((const long long*)ep)[idx];
  return ((const int*)ep)[idx];
}

// Per-block int64-vs-int32 detection: sample hi words of first 256 entries.
__device__ __forceinline__ int detect64(const void* edges, int* sflag) {
  int t = threadIdx.x;
  if (t == 0) *sflag = 1;
  __syncthreads();
  if (t < 256 && ((const int*)edges)[2 * t + 1] != 0) *sflag = 0;  // benign race
  __syncthreads();
  return *sflag;
}

// Pass A: per-block bucket histogram (LDS atomics), coalesced cnt write.
__global__ __launch_bounds__(256) void countA_kernel(const void* edges,
                                                     int* __restrict__ cnt,
                                                     long long E, int nbuck) {
  __shared__ int h[256];
  __shared__ int sflag;
  int is64 = detect64(edges, &sflag);
  int t = threadIdx.x;
  h[t] = 0;
  __syncthreads();
  long long stride = (long long)GB * 256;
  for (long long i = (long long)blockIdx.x * 256 + t; i < E; i += stride) {
    int dst = edge_at(edges, is64, E + i);
    atomicAdd(&h[dst >> SHIFT], 1);
  }
  __syncthreads();
  if (t < nbuck) cnt[blockIdx.x * nbuck + t] = h[t];
}

// Pass B1: bucket totals + exclusive scan -> bucket_base; also row_ptr[N]=E.
__global__ __launch_bounds__(256) void scanB1_kernel(const int* __restrict__ cnt,
                                                     int* __restrict__ bucket_base,
                                                     int* __restrict__ row_ptr,
                                                     int nbuck, int N) {
  __shared__ int sm[256];
  int t = threadIdx.x;
  int total = 0;
  if (t < nbuck)
    for (int g = 0; g < GB; ++g) total += cnt[g * nbuck + t];
  sm[t] = total;
  __syncthreads();
  for (int o = 1; o < 256; o <<= 1) {
    int x = (t >= o) ? sm[t - o] : 0;
    __syncthreads();
    sm[t] += x;
    __syncthreads();
  }
  if (t < nbuck) bucket_base[t] = sm[t] - total;
  if (t == nbuck - 1) {
    bucket_base[nbuck] = sm[t];
    row_ptr[N] = sm[t];
  }
}

// Pass B2: per-(block,bucket) cursors: cur[g][b] = base[b] + prefix_g cnt[g][b].
__global__ __launch_bounds__(256) void scanB2_kernel(const int* __restrict__ cnt,
                                                     const int* __restrict__ bucket_base,
                                                     int* __restrict__ cur, int nbuck) {
  __shared__ int sm[256];
  int b = blockIdx.x, t = threadIdx.x;
  int v = cnt[t * nbuck + b];
  sm[t] = v;
  __syncthreads();
  for (int o = 1; o < 256; o <<= 1) {
    int x = (t >= o) ? sm[t - o] : 0;
    __syncthreads();
    sm[t] += x;
    __syncthreads();
  }
  cur[t * nbuck + b] = bucket_base[b] + sm[t] - v;
}

// Pass C: scatter edges into bucket-contiguous tmp arrays (LDS cursors).
__global__ __launch_bounds__(256) void scatterC_kernel(const void* edges,
                                                       const int* __restrict__ cur,
                                                       int* __restrict__ tmps,
                                                       u16* __restrict__ tmpd,
                                                       long long E, int nbuck) {
  __shared__ int c[256];
  __shared__ int sflag;
  int is64 = detect64(edges, &sflag);
  int t = threadIdx.x;
  if (t < nbuck) c[t] = cur[blockIdx.x * nbuck + t];
  __syncthreads();
  long long stride = (long long)GB * 256;
  for (long long i = (long long)blockIdx.x * 256 + t; i < E; i += stride) {
    int src = edge_at(edges, is64, i);
    int dst = edge_at(edges, is64, E + i);
    int bk = dst >> SHIFT;
    int pos = atomicAdd(&c[bk], 1);
    tmps[pos] = src;
    tmpd[pos] = (u16)(dst & ((1 << SHIFT) - 1));
  }
}

// Pass D: per-bucket fine counting sort, all cursors in LDS.
// sorted_src stores PRE-SHIFTED byte offsets: src<<6 (64B granularity).
__global__ __launch_bounds__(512) void finesort_kernel(const int* __restrict__ tmps,
                                                       const u16* __restrict__ tmpd,
                                                       const int* __restrict__ bucket_base,
                                                       int* __restrict__ row_ptr,
                                                       float* __restrict__ deg_inv,
                                                       int* __restrict__ sorted_src, int N) {
  __shared__ int dg[512];
  __shared__ int sm[512];
  int b = blockIdx.x, t = threadIdx.x;
  int s = bucket_base[b], e = bucket_base[b + 1];
  dg[t] = 0;
  __syncthreads();
  for (int i = s + t; i < e; i += 512) atomicAdd(&dg[tmpd[i]], 1);
  __syncthreads();
  int v = dg[t];
  sm[t] = v;
  __syncthreads();
  for (int o = 1; o < 512; o <<= 1) {
    int x = (t >= o) ? sm[t - o] : 0;
    __syncthreads();
    sm[t] += x;
    __syncthreads();
  }
  int excl = sm[t] - v;
  int node = (b << SHIFT) + t;
  if (node < N) {
    row_ptr[node] = s + excl;
    deg_inv[node] = (v > 0) ? (1.0f / (float)v) : 0.0f;
  }
  sm[t] = s + excl;  // own cell only: becomes the scatter cursor
  __syncthreads();
  for (int i = s + t; i < e; i += 512) {
    int l = tmpd[i];
    int pos = atomicAdd(&sm[l], 1);
    sorted_src[pos] = tmps[i] << 6;   // byte offset, 64B unit
  }
}

// ---------------------------------------------------------------------------
// MFMA GEMM, stage-B-once + M-loop, double-buffered A, lgkm-only barrier.
// OPERAND-SWAPPED mfma(b,a): lane holds 4 consecutive output COLS ->
// u8x4 / u16x4 vector epilogue stores. cl fp8 row-major; cr bf16 row-major.
// ---------------------------------------------------------------------------
template <bool IN_BF16>
__global__ __launch_bounds__(256) void gemm_loop_kernel(
    const void* __restrict__ Xv, const float* __restrict__ Wl, const float* __restrict__ Wr,
    u8* __restrict__ cl, u16* __restrict__ cr, int N, int split, int nr, int mtiles) {
  __shared__ u16 Bs[128][136];
  __shared__ u16 As[2][64][136];
  int tid = threadIdx.x;
  int cb = blockIdx.y * 128;

  const float* Xf = (const float*)Xv;
  const u16* Xb = (const u16*)Xv;
  float4 af[8];
  u16x8 ab[4];

  auto loadA = [&](int mt) {
    long long rb = (long long)mt * 64;
    if constexpr (IN_BF16) {
#pragma unroll
      for (int k = 0; k < 4; ++k) {
        int i = tid + (k << 8);
        int r = i >> 4, c8 = (i & 15) << 3;
        long long gr = rb + r;
        if (gr >= N) gr = N - 1;
        ab[k] = *(const u16x8*)(Xb + gr * 128 + c8);
      }
    } else {
#pragma unroll
      for (int k = 0; k < 8; ++k) {
        int i = tid + (k << 8);
        int r = i >> 5, c4 = (i & 31) << 2;
        long long gr = rb + r;
        if (gr >= N) gr = N - 1;
        af[k] = *(const float4*)(Xf + gr * 128 + c4);
      }
    }
  };
  auto writeA = [&](int buf) {
    if constexpr (IN_BF16) {
#pragma unroll
      for (int k = 0; k < 4; ++k) {
        int i = tid + (k << 8);
        int r = i >> 4, c8 = (i & 15) << 3;
        *(u16x8*)&As[buf][r][c8] = ab[k];
      }
    } else {
#pragma unroll
      for (int k = 0; k < 8; ++k) {
        int i = tid + (k << 8);
        int r = i >> 5, c4 = (i & 31) << 2;
        uint2 p = {cvt_pk_bf16(af[k].x, af[k].y), cvt_pk_bf16(af[k].z, af[k].w)};
        *(uint2*)&As[buf][r][c4] = p;
      }
    }
  };

  if (blockIdx.x < mtiles) loadA(blockIdx.x);

  // stage B once (weights; L2-resident), packed bf16 converts
  for (int i = tid; i < 128 * 32; i += 256) {
    int r = i >> 5, c4 = (i & 31) << 2;
    int gc = cb + r;
    const float* wrow = (gc < split) ? (Wl + (long long)gc * 128)
                                     : (Wr + (long long)(gc - split) * 128);
    float4 v = *(const float4*)(wrow + c4);
    uint2 p = {cvt_pk_bf16(v.x, v.y), cvt_pk_bf16(v.z, v.w)};
    *(uint2*)&Bs[r][c4] = p;
  }

  int wv = tid >> 6, l = tid & 63;
  int wr = (wv & 1) * 32, wc = (wv >> 1) * 64;
  int lr = l & 15, lk = (l >> 4) * 8;

  int lt = 0;
  for (int mt = blockIdx.x; mt < mtiles; mt += gridDim.x, ++lt) {
    int buf = lt & 1;
    writeA(buf);                       // consume prefetch regs -> LDS
    int nmt = mt + gridDim.x;
    if (nmt < mtiles) loadA(nmt);      // next loads stay in flight across barrier
    asm volatile("s_waitcnt lgkmcnt(0)" ::: "memory");  // ds_writes visible
    __builtin_amdgcn_s_barrier();      // NO vmcnt drain

    f32x4 acc[2][4];
#pragma unroll
    for (int i = 0; i < 2; ++i)
#pragma unroll
      for (int j = 0; j < 4; ++j)
#pragma unroll
        for (int r = 0; r < 4; ++r) acc[i][j][r] = 0.f;

#pragma unroll
    for (int ks = 0; ks < 4; ++ks) {
      bf16x8 a[2], b[4];
#pragma unroll
      for (int i = 0; i < 2; ++i)
        a[i] = *(const bf16x8*)&As[buf][wr + i * 16 + lr][ks * 32 + lk];
#pragma unroll
      for (int j = 0; j < 4; ++j)
        b[j] = *(const bf16x8*)&Bs[wc + j * 16 + lr][ks * 32 + lk];
      // OPERAND-SWAPPED: output row <- lane&15 (A), cols <- reg quad (B)
#pragma unroll
      for (int i = 0; i < 2; ++i)
#pragma unroll
        for (int j = 0; j < 4; ++j)
          acc[i][j] = __builtin_amdgcn_mfma_f32_16x16x32_bf16(b[j], a[i], acc[i][j], 0, 0, 0);
    }

    // Swapped C/D layout: row = lane&15, col = (lane>>4)*4 + reg
    long long rb = (long long)mt * 64;
#pragma unroll
    for (int i = 0; i < 2; ++i) {
      long long gr = rb + wr + i * 16 + (l & 15);
      if (gr < N) {
#pragma unroll
        for (int j = 0; j < 4; ++j) {
          int gc0 = cb + wc + j * 16 + ((l >> 4) << 2);
          if (gc0 < split) {
            unsigned p = cvt_pk_fp8x4(acc[i][j][0], acc[i][j][1], acc[i][j][2], acc[i][j][3]);
            *(unsigned*)(cl + gr * split + gc0) = p;
          } else {
            uint2 p = {cvt_pk_bf16(acc[i][j][0], acc[i][j][1]),
                       cvt_pk_bf16(acc[i][j][2], acc[i][j][3])};
            *(uint2*)(cr + gr * nr + (gc0 - split)) = p;
          }
        }
      }
    }
  }
}

// Layer-1 aggregate + combine + ReLU. Wave per node. 4 quarters x 16 lanes;
// lane loads uint2 (8 fp8 ch) -> 4 edges per VMEM instruction, unroll 2.
__global__ __launch_bounds__(256) void agg1_kernel(const u8* __restrict__ t1l,
                                                   const u16* __restrict__ t1r,
                                                   const int* __restrict__ row_ptr,
                                                   const int* __restrict__ srcoff,
                                                   const float* __restrict__ deg_inv,
                                                   const float* __restrict__ b1,
                                                   u16* __restrict__ h, int N) {
  int node = (int)(((long long)blockIdx.x * 256 + threadIdx.x) >> 6);
  int lane = threadIdx.x & 63;
  if (node >= N) return;
  int q = lane >> 4;        // edge slot within 4-edge group
  int c = lane & 15;        // channel octet: ch c*8 .. c*8+7
  unsigned loff = (unsigned)c * 8;

  int beg = row_ptr[node], end = row_ptr[node + 1];
  float di = deg_inv[node];
  u16x8 tr = *(const u16x8*)(t1r + (long long)node * 128 + c * 8);
  f32x4 bb0 = *(const f32x4*)(b1 + c * 8);
  f32x4 bb1 = *(const f32x4*)(b1 + c * 8 + 4);

  f32x2 a0 = {0.f, 0.f}, a1 = {0.f, 0.f}, a2 = {0.f, 0.f}, a3 = {0.f, 0.f};
  int e = beg + q;
  for (; e + 4 < end; e += 8) {   // this quarter: edges e and e+4
    int o0 = srcoff[e], o1 = srcoff[e + 4];
    uint2 w0 = *(const uint2*)(t1l + ((unsigned)(o0 << 1) + loff));
    uint2 w1 = *(const uint2*)(t1l + ((unsigned)(o1 << 1) + loff));
    a0 += __builtin_amdgcn_cvt_pk_f32_fp8((int)w0.x, 0);
    a1 += __builtin_amdgcn_cvt_pk_f32_fp8((int)w0.x, 1);
    a2 += __builtin_amdgcn_cvt_pk_f32_fp8((int)w0.y, 0);
    a3 += __builtin_amdgcn_cvt_pk_f32_fp8((int)w0.y, 1);
    a0 += __builtin_amdgcn_cvt_pk_f32_fp8((int)w1.x, 0);
    a1 += __builtin_amdgcn_cvt_pk_f32_fp8((int)w1.x, 1);
    a2 += __builtin_amdgcn_cvt_pk_f32_fp8((int)w1.y, 0);
    a3 += __builtin_amdgcn_cvt_pk_f32_fp8((int)w1.y, 1);
  }
  for (; e < end; e += 4) {
    int o0 = srcoff[e];
    uint2 w0 = *(const uint2*)(t1l + ((unsigned)(o0 << 1) + loff));
    a0 += __builtin_amdgcn_cvt_pk_f32_fp8((int)w0.x, 0);
    a1 += __builtin_amdgcn_cvt_pk_f32_fp8((int)w0.x, 1);
    a2 += __builtin_amdgcn_cvt_pk_f32_fp8((int)w0.y, 0);
    a3 += __builtin_amdgcn_cvt_pk_f32_fp8((int)w0.y, 1);
  }
#pragma unroll
  for (int j = 0; j < 2; ++j) {
    a0[j] += __shfl_xor(a0[j], 16); a0[j] += __shfl_xor(a0[j], 32);
    a1[j] += __shfl_xor(a1[j], 16); a1[j] += __shfl_xor(a1[j], 32);
    a2[j] += __shfl_xor(a2[j], 16); a2[j] += __shfl_xor(a2[j], 32);
    a3[j] += __shfl_xor(a3[j], 16); a3[j] += __shfl_xor(a3[j], 32);
  }
  if (q == 0) {
    u16x8 o;
    o[0] = f2b(fmaxf(a0[0] * di + b2f(tr[0]) + bb0[0], 0.f));
    o[1] = f2b(fmaxf(a0[1] * di + b2f(tr[1]) + bb0[1], 0.f));
    o[2] = f2b(fmaxf(a1[0] * di + b2f(tr[2]) + bb0[2], 0.f));
    o[3] = f2b(fmaxf(a1[1] * di + b2f(tr[3]) + bb0[3], 0.f));
    o[4] = f2b(fmaxf(a2[0] * di + b2f(tr[4]) + bb1[0], 0.f));
    o[5] = f2b(fmaxf(a2[1] * di + b2f(tr[5]) + bb1[1], 0.f));
    o[6] = f2b(fmaxf(a3[0] * di + b2f(tr[6]) + bb1[2], 0.f));
    o[7] = f2b(fmaxf(a3[1] * di + b2f(tr[7]) + bb1[3], 0.f));
    *(u16x8*)(h + (long long)node * 128 + c * 8) = o;
  }
}

// Layer-2 aggregate + combine. Wave per node. 4 quarters x 16 lanes; lane
// loads uint (4 fp8 ch) -> 4 edges per VMEM instruction, unroll 2.
__global__ __launch_bounds__(256) void agg2_kernel(const u8* __restrict__ t3l,
                                                   const u16* __restrict__ t3r,
                                                   const int* __restrict__ row_ptr,
                                                   const int* __restrict__ srcoff,
                                                   const float* __restrict__ deg_inv,
                                                   const float* __restrict__ b2,
                                                   float* __restrict__ out, int N) {
  int node = (int)(((long long)blockIdx.x * 256 + threadIdx.x) >> 6);
  int lane = threadIdx.x & 63;
  if (node >= N) return;
  int q = lane >> 4;        // edge slot
  int c = lane & 15;        // channel quad: ch c*4 .. c*4+3
  unsigned loff = (unsigned)c * 4;

  int beg = row_ptr[node], end = row_ptr[node + 1];
  float di = deg_inv[node];
  u16x4 tr = *(const u16x4*)(t3r + (long long)node * 64 + c * 4);
  f32x4 bb = *(const f32x4*)(b2 + c * 4);

  f32x2 a0 = {0.f, 0.f}, a1 = {0.f, 0.f};
  int e = beg + q;
  for (; e + 4 < end; e += 8) {
    int o0 = srcoff[e], o1 = srcoff[e + 4];
    unsigned w0 = *(const unsigned*)(t3l + ((unsigned)o0 + loff));
    unsigned w1 = *(const unsigned*)(t3l + ((unsigned)o1 + loff));
    a0 += __builtin_amdgcn_cvt_pk_f32_fp8((int)w0, 0);
    a1 += __builtin_amdgcn_cvt_pk_f32_fp8((int)w0, 1);
    a0 += __builtin_amdgcn_cvt_pk_f32_fp8((int)w1, 0);
    a1 += __builtin_amdgcn_cvt_pk_f32_fp8((int)w1, 1);
  }
  for (; e < end; e += 4) {
    int o0 = srcoff[e];
    unsigned w0 = *(const unsigned*)(t3l + ((unsigned)o0 + loff));
    a0 += __builtin_amdgcn_cvt_pk_f32_fp8((int)w0, 0);
    a1 += __builtin_amdgcn_cvt_pk_f32_fp8((int)w0, 1);
  }
#pragma unroll
  for (int j = 0; j < 2; ++j) {
    a0[j] += __shfl_xor(a0[j], 16); a0[j] += __shfl_xor(a0[j], 32);
    a1[j] += __shfl_xor(a1[j], 16); a1[j] += __shfl_xor(a1[j], 32);
  }
  if (q == 0) {
    f32x4 o;
    o[0] = a0[0] * di + b2f(tr[0]) + bb[0];
    o[1] = a0[1] * di + b2f(tr[1]) + bb[1];
    o[2] = a1[0] * di + b2f(tr[2]) + bb[2];
    o[3] = a1[1] * di + b2f(tr[3]) + bb[3];
    *(f32x4*)(out + (long long)node * 64 + c * 4) = o;
  }
}

extern "C" void kernel_launch(void* const* d_in, const int* in_sizes, int n_in,
                              void* d_out, int out_size, void* d_ws, size_t ws_size,
                              hipStream_t stream) {
  const float* x = (const float*)d_in[0];
  const void* edges = d_in[1];
  const float* W1l = (const float*)d_in[2];
  const float* W1r = (const float*)d_in[3];
  const float* b1 = (const float*)d_in[4];
  const float* W2l = (const float*)d_in[5];
  const float* W2r = (const float*)d_in[6];
  const float* b2 = (const float*)d_in[7];
  float* out = (float*)d_out;

  int N = in_sizes[0] / 128;
  long long E = (long long)in_sizes[1] / 2;
  int nbuck = (N + (1 << SHIFT) - 1) >> SHIFT;  // 196 for N=100000 (<=256 required)

  auto align = [](size_t v) { return (v + 255) & ~(size_t)255; };
  char* ws = (char*)d_ws;
  size_t o = 0;
  int* bucket_base = (int*)(ws + o);  o += align((size_t)(nbuck + 1) * 4);
  int* cnt = (int*)(ws + o);          o += align((size_t)GB * nbuck * 4);
  int* cur = (int*)(ws + o);          o += align((size_t)GB * nbuck * 4);
  int* row_ptr = (int*)(ws + o);      o += align((size_t)(N + 1) * 4);
  float* deg_inv = (float*)(ws + o);  o += align((size_t)N * 4);
  int* sorted_src = (int*)(ws + o);   o += align((size_t)E * 4);
  int* tmps = (int*)(ws + o);         o += align((size_t)E * 4);
  u16* tmpd = (u16*)(ws + o);         o += align((size_t)E * 2);
  u8* t1l = (u8*)(ws + o);            o += align((size_t)N * 128);  // [N][128] fp8
  u16* t1r = (u16*)(ws + o);          o += align((size_t)N * 128 * 2);
  u16* h = (u16*)(ws + o);            o += align((size_t)N * 128 * 2);
  u8* t3l = t1l;     // aliases: t1 dead once h computed; [N][64] fp8
  u16* t3r = t1r;

  countA_kernel<<<GB, 256, 0, stream>>>(edges, cnt, E, nbuck);
  scanB1_kernel<<<1, 256, 0, stream>>>(cnt, bucket_base, row_ptr, nbuck, N);
  scanB2_kernel<<<nbuck, 256, 0, stream>>>(cnt, bucket_base, cur, nbuck);
  scatterC_kernel<<<GB, 256, 0, stream>>>(edges, cur, tmps, tmpd, E, nbuck);
  finesort_kernel<<<nbuck, 512, 0, stream>>>(tmps, tmpd, bucket_base, row_ptr, deg_inv,
                                             sorted_src, N);

  int mb = (N + 63) / 64;
  // Layer 1: [t1l | t1r] = x @ [W1_l | W1_r]^T  (split=128, nr=128, 2 col-tiles)
  gemm_loop_kernel<false><<<dim3(256, 2), 256, 0, stream>>>(x, W1l, W1r, t1l, t1r, N, 128, 128, mb);
  agg1_kernel<<<(N + 3) / 4, 256, 0, stream>>>(t1l, t1r, row_ptr, sorted_src, deg_inv, b1, h, N);

  // Layer 2: [t3l | t3r] = h @ [W2_l | W2_r]^T  (split=64, nr=64, 1 col-tile)
  gemm_loop_kernel<true><<<dim3(512, 1), 256, 0, stream>>>(h, W2l, W2r, t3l, t3r, N, 64, 64, mb);
  agg2_kernel<<<(N + 3) / 4, 256, 0, stream>>>(t3l, t3r, row_ptr, sorted_src, deg_inv, b2, out, N);
}